// Round 1
// baseline (156.110 us; speedup 1.0000x reference)
//
#include <hip/hip_runtime.h>
#include <math.h>

#define Bv  4
#define Cv  64
#define DCv 32
#define Fv  128
#define Tv  512
#define FT  (Fv * Tv)

// Swizzled Q^T layout in LDS: column-owner dim t (0..511), element dim k (0..31).
// float4 group j of column t lives at t*32 + ((j ^ (t&7))<<2).  16B-aligned, banks balanced.
__device__ __forceinline__ int qoff4(int t, int j) { return t * 32 + ((j ^ (t & 7)) << 2); }
__device__ __forceinline__ int qoff1(int t, int k) { return t * 32 + (((k >> 2) ^ (t & 7)) << 2) + (k & 3); }

__global__ __launch_bounds__(512, 2)
void fused_attn_kernel(const float* __restrict__ inp,
                       const float* __restrict__ w1, const float* __restrict__ b1,
                       const float* __restrict__ g1, const float* __restrict__ be1,
                       const float* __restrict__ m1, const float* __restrict__ v1,
                       const float* __restrict__ a1,
                       const float* __restrict__ wp, const float* __restrict__ bp,
                       const float* __restrict__ g2, const float* __restrict__ be2,
                       const float* __restrict__ m2, const float* __restrict__ v2,
                       const float* __restrict__ a2,
                       float* __restrict__ out)
{
    __shared__ __align__(16) float sQt[Tv * DCv];   // 64 KB: Q^T, then O, then P (in place)
    __shared__ __align__(16) float sM[DCv * DCv];   // 4 KB
    __shared__ float sS1[DCv], sT1[DCv], sS2[Cv], sT2[Cv];

    const int tid = threadIdx.x;
    const int bf  = blockIdx.x;
    const int b   = bf >> 7;   // / F
    const int f   = bf & 127;  // % F

    // ---------------- setup: fold BN affine, zero sM ----------------
    if (tid < DCv) {
        float s = g1[tid] / sqrtf(v1[tid] + 1e-5f);
        sS1[tid] = s;
        sT1[tid] = (b1[tid] - m1[tid]) * s + be1[tid];
    } else if (tid < DCv + Cv) {
        int o = tid - DCv;
        float s = g2[o] / sqrtf(v2[o] + 1e-5f);
        sS2[o] = s;
        sT2[o] = (bp[o] - m2[o]) * s + be2[o];
    }
    sM[tid] = 0.f;
    sM[tid + 512] = 0.f;
    const float alpha1 = a1[0];
    const float alpha2 = a2[0];
    __syncthreads();

    const int t = tid;  // this thread owns time-column t

    // ---------------- Phase A: conv1 + BN + PReLU -> Q^T in LDS ----------------
    {
        float acc[DCv];
        #pragma unroll
        for (int c = 0; c < DCv; ++c) acc[c] = 0.f;

        #pragma unroll
        for (int half = 0; half < 2; ++half) {
            float x[32];
            const float* px = inp + ((size_t)(b * Cv + half * 32) * Fv + f) * Tv + t;
            #pragma unroll
            for (int i = 0; i < 32; ++i) x[i] = px[i * FT];
            #pragma unroll 4
            for (int c = 0; c < DCv; ++c) {
                const float* wr = w1 + c * Cv + half * 32;  // uniform -> scalar loads
                float a = acc[c];
                #pragma unroll
                for (int i = 0; i < 32; ++i) a = fmaf(wr[i], x[i], a);
                acc[c] = a;
            }
        }
        #pragma unroll
        for (int j = 0; j < 8; ++j) {
            float z0 = fmaf(acc[4*j+0], sS1[4*j+0], sT1[4*j+0]);
            float z1 = fmaf(acc[4*j+1], sS1[4*j+1], sT1[4*j+1]);
            float z2 = fmaf(acc[4*j+2], sS1[4*j+2], sT1[4*j+2]);
            float z3 = fmaf(acc[4*j+3], sS1[4*j+3], sT1[4*j+3]);
            float4 v;
            v.x = z0 >= 0.f ? z0 : alpha1 * z0;
            v.y = z1 >= 0.f ? z1 : alpha1 * z1;
            v.z = z2 >= 0.f ? z2 : alpha1 * z2;
            v.w = z3 >= 0.f ? z3 : alpha1 * z3;
            *(float4*)&sQt[qoff4(t, j)] = v;
        }
    }
    __syncthreads();

    // ---------------- Phase B: M = Q Q^T / sqrt(32) ----------------
    {
        const int w = tid >> 6, l = tid & 63;
        const int c1b = l >> 3;   // 4-row block of M
        const int c2b = l & 7;    // 4-col block of M
        float4 r0 = {0,0,0,0}, r1 = {0,0,0,0}, r2 = {0,0,0,0}, r3 = {0,0,0,0};
        const int kbase = w * 64;
        for (int i = 0; i < 64; ++i) {
            const int k = kbase + i;
            const float4 qa = *(const float4*)&sQt[qoff4(k, c1b)];
            const float4 qb = *(const float4*)&sQt[qoff4(k, c2b)];
            r0.x = fmaf(qa.x, qb.x, r0.x); r0.y = fmaf(qa.x, qb.y, r0.y);
            r0.z = fmaf(qa.x, qb.z, r0.z); r0.w = fmaf(qa.x, qb.w, r0.w);
            r1.x = fmaf(qa.y, qb.x, r1.x); r1.y = fmaf(qa.y, qb.y, r1.y);
            r1.z = fmaf(qa.y, qb.z, r1.z); r1.w = fmaf(qa.y, qb.w, r1.w);
            r2.x = fmaf(qa.z, qb.x, r2.x); r2.y = fmaf(qa.z, qb.y, r2.y);
            r2.z = fmaf(qa.z, qb.z, r2.z); r2.w = fmaf(qa.z, qb.w, r2.w);
            r3.x = fmaf(qa.w, qb.x, r3.x); r3.y = fmaf(qa.w, qb.y, r3.y);
            r3.z = fmaf(qa.w, qb.z, r3.z); r3.w = fmaf(qa.w, qb.w, r3.w);
        }
        const float inv = 0.17677669529663687f;  // 1/sqrt(32)
        float* m0 = &sM[(c1b * 4 + 0) * DCv + c2b * 4];
        float* m1r = &sM[(c1b * 4 + 1) * DCv + c2b * 4];
        float* m2r = &sM[(c1b * 4 + 2) * DCv + c2b * 4];
        float* m3r = &sM[(c1b * 4 + 3) * DCv + c2b * 4];
        atomicAdd(m0 + 0, r0.x * inv); atomicAdd(m0 + 1, r0.y * inv);
        atomicAdd(m0 + 2, r0.z * inv); atomicAdd(m0 + 3, r0.w * inv);
        atomicAdd(m1r + 0, r1.x * inv); atomicAdd(m1r + 1, r1.y * inv);
        atomicAdd(m1r + 2, r1.z * inv); atomicAdd(m1r + 3, r1.w * inv);
        atomicAdd(m2r + 0, r2.x * inv); atomicAdd(m2r + 1, r2.y * inv);
        atomicAdd(m2r + 2, r2.z * inv); atomicAdd(m2r + 3, r2.w * inv);
        atomicAdd(m3r + 0, r3.x * inv); atomicAdd(m3r + 1, r3.y * inv);
        atomicAdd(m3r + 2, r3.z * inv); atomicAdd(m3r + 3, r3.w * inv);
    }
    __syncthreads();

    // ---------------- Phase C: O = M * Q (in place over sQt, per-column) ----------------
    {
        float q[DCv];
        #pragma unroll
        for (int j = 0; j < 8; ++j) {
            float4 v = *(const float4*)&sQt[qoff4(t, j)];
            q[4*j] = v.x; q[4*j+1] = v.y; q[4*j+2] = v.z; q[4*j+3] = v.w;
        }
        #pragma unroll 2
        for (int j = 0; j < 8; ++j) {
            const float4* M0 = (const float4*)&sM[(4*j+0) * DCv];
            const float4* M1 = (const float4*)&sM[(4*j+1) * DCv];
            const float4* M2 = (const float4*)&sM[(4*j+2) * DCv];
            const float4* M3 = (const float4*)&sM[(4*j+3) * DCv];
            float d0 = 0.f, d1 = 0.f, d2 = 0.f, d3 = 0.f;
            #pragma unroll
            for (int kk = 0; kk < 8; ++kk) {
                float4 a = M0[kk], bq = M1[kk], c = M2[kk], d = M3[kk];
                d0 = fmaf(a.x, q[4*kk], d0); d0 = fmaf(a.y, q[4*kk+1], d0);
                d0 = fmaf(a.z, q[4*kk+2], d0); d0 = fmaf(a.w, q[4*kk+3], d0);
                d1 = fmaf(bq.x, q[4*kk], d1); d1 = fmaf(bq.y, q[4*kk+1], d1);
                d1 = fmaf(bq.z, q[4*kk+2], d1); d1 = fmaf(bq.w, q[4*kk+3], d1);
                d2 = fmaf(c.x, q[4*kk], d2); d2 = fmaf(c.y, q[4*kk+1], d2);
                d2 = fmaf(c.z, q[4*kk+2], d2); d2 = fmaf(c.w, q[4*kk+3], d2);
                d3 = fmaf(d.x, q[4*kk], d3); d3 = fmaf(d.y, q[4*kk+1], d3);
                d3 = fmaf(d.z, q[4*kk+2], d3); d3 = fmaf(d.w, q[4*kk+3], d3);
            }
            float4 v; v.x = d0; v.y = d1; v.z = d2; v.w = d3;
            *(float4*)&sQt[qoff4(t, j)] = v;
        }
    }
    __syncthreads();

    // ---------------- Phase D: mask + softmax over t (rows of O) ----------------
    {
        const int w = tid >> 6, l = tid & 63;
        int limit = f + (Tv - Fv + 1);         // valid: t < limit
        if (limit > Tv) limit = Tv;
        #pragma unroll
        for (int r = 0; r < 4; ++r) {
            const int c = w * 4 + r;
            float vals[8];
            float mx = -INFINITY;
            #pragma unroll
            for (int ch = 0; ch < 8; ++ch) {
                const int tt = ch * 64 + l;
                float v = (tt < limit) ? sQt[qoff1(tt, c)] : -INFINITY;
                vals[ch] = v;
                mx = fmaxf(mx, v);
            }
            #pragma unroll
            for (int s = 1; s < 64; s <<= 1) mx = fmaxf(mx, __shfl_xor(mx, s));
            float sum = 0.f;
            #pragma unroll
            for (int ch = 0; ch < 8; ++ch) {
                const int tt = ch * 64 + l;
                float e = (tt < limit) ? __expf(vals[ch] - mx) : 0.f;
                vals[ch] = e;
                sum += e;
            }
            #pragma unroll
            for (int s = 1; s < 64; s <<= 1) sum += __shfl_xor(sum, s);
            const float rinv = 1.f / sum;
            #pragma unroll
            for (int ch = 0; ch < 8; ++ch) {
                const int tt = ch * 64 + l;
                sQt[qoff1(tt, c)] = vals[ch] * rinv;
            }
        }
    }
    __syncthreads();

    // ---------------- Phase E: conv2 + BN + PReLU + residual -> out ----------------
    {
        float p[DCv];
        #pragma unroll
        for (int j = 0; j < 8; ++j) {
            float4 v = *(const float4*)&sQt[qoff4(t, j)];
            p[4*j] = v.x; p[4*j+1] = v.y; p[4*j+2] = v.z; p[4*j+3] = v.w;
        }
        #pragma unroll
        for (int half = 0; half < 2; ++half) {
            const float* pin = inp + ((size_t)(b * Cv + half * 32) * Fv + f) * Tv + t;
            float*       pot = out + ((size_t)(b * Cv + half * 32) * Fv + f) * Tv + t;
            float rin[32];
            #pragma unroll
            for (int i = 0; i < 32; ++i) rin[i] = pin[i * FT];
            #pragma unroll 4
            for (int oo = 0; oo < 32; ++oo) {
                const int o = half * 32 + oo;
                const float* wr = wp + o * DCv;  // uniform -> scalar loads
                float a = 0.f;
                #pragma unroll
                for (int c2 = 0; c2 < DCv; ++c2) a = fmaf(wr[c2], p[c2], a);
                float z = fmaf(a, sS2[o], sT2[o]);
                z = z >= 0.f ? z : alpha2 * z;
                pot[oo * FT] = z + rin[oo];
            }
        }
    }
}

extern "C" void kernel_launch(void* const* d_in, const int* in_sizes, int n_in,
                              void* d_out, int out_size, void* d_ws, size_t ws_size,
                              hipStream_t stream) {
    const float* inp = (const float*)d_in[0];
    const float* w1  = (const float*)d_in[1];
    const float* b1  = (const float*)d_in[2];
    const float* g1  = (const float*)d_in[3];
    const float* be1 = (const float*)d_in[4];
    const float* m1  = (const float*)d_in[5];
    const float* v1  = (const float*)d_in[6];
    const float* a1  = (const float*)d_in[7];
    const float* wp  = (const float*)d_in[8];
    const float* bp  = (const float*)d_in[9];
    const float* g2  = (const float*)d_in[10];
    const float* be2 = (const float*)d_in[11];
    const float* m2  = (const float*)d_in[12];
    const float* v2  = (const float*)d_in[13];
    const float* a2  = (const float*)d_in[14];

    fused_attn_kernel<<<dim3(Bv * Fv), dim3(512), 0, stream>>>(
        inp, w1, b1, g1, be1, m1, v1, a1, wp, bp, g2, be2, m2, v2, a2, (float*)d_out);
}